// Round 4
// baseline (1098.201 us; speedup 1.0000x reference)
//
#include <hip/hip_runtime.h>

// DilateAttention: B=16, C=384 (12 heads x 32), H=W=56, 3x3 window, dil=2,
// reflect pad. Memory-bound; ideal HBM ~308 MB -> ~49 us floor.
//
// R4 = R3 streaming skeleton (block = (b, head, 8-row band); k/v d-chunks of
// 8 staged to LDS via async global_load_lds width-16, double-buffered) plus:
//  1. paired LDS window reads: per row, p[0],p[2],p[4] from clamped col base
//     (ds_read2_b32 + ds_read_b32) with 3 cndmask selects for the 4
//     reflection-edge lanes -> LDS-pipe time -28%.
//  2. register O[32] accumulator; single 128B contiguous store per thread at
//     the end -> removes the 1.6x partial-line write amplification (123->77MB).
//  3. q[32] loaded upfront (hidden under chunk-0 DMA; regs reused for O).

#define BB 16
#define CH 384
#define HH 56
#define WW 56
#define NH 12
#define DD 32
#define HW (HH * WW)
#define KSQ 9
#define SCALE 0.17677669529663687f  // 32^-0.5

#define BAND 8                 // pixel rows per block
#define DCH 8                  // d-channels per staged chunk
#define NCHUNK (DD / DCH)      // 4
#define MAXROWS 12             // band + 2*halo
#define SLICE (MAXROWS * WW)   // floats per d-slice in LDS (672)
#define LBUF (DCH * SLICE)     // floats per buffer (5376)

__device__ __forceinline__ void async16(const void* g, void* l) {
    __builtin_amdgcn_global_load_lds(
        (const __attribute__((address_space(1))) void*)g,
        (__attribute__((address_space(3))) void*)l, 16, 0, 0);
}

// Stage one d-chunk (DCH planes x nr rows x 56 cols) into ldsbuf.
// plane0 points at row `lo` of the first d-plane of the chunk. Sbytes = nr*224.
// Each d-slice is covered by three 1KB wave-instrs: offsets 0, 1024, S-1024
// (the third overlaps the second; duplicate writes carry identical data).
__device__ __forceinline__ void stage_chunk(const float* __restrict__ plane0,
                                            float* ldsbuf, int Sbytes,
                                            int wv, int lane) {
    const int lo16 = lane * 16;
    for (int s = wv; s < DCH; s += 7) {      // 7 waves cover 8 slices
        const char* g = (const char*)(plane0 + s * HW);
        char* l = (char*)(ldsbuf + s * SLICE);
        async16(g + lo16, l + lo16);
        async16(g + 1024 + lo16, l + 1024 + lo16);
        const int t = Sbytes - 1024;
        async16(g + t + lo16, l + t + lo16);
    }
}

// 3-col window read: A,B,C at dword offsets 0,2,4 from a clamped per-lane
// base; role selects fix the reflected edge lanes (w in {0,1,54,55}).
#define WIN3(p, v0, v1, v2)                          \
    do {                                             \
        float A_ = (p)[0], B_ = (p)[2], C_ = (p)[4]; \
        v0 = isW0 ? B_ : A_;                         \
        v1 = wle1 ? A_ : B_;                         \
        v2 = isW55 ? A_ : (midB ? B_ : C_);          \
    } while (0)

__global__ __launch_bounds__(448, 4)
void dilate_attn_kernel(const float* __restrict__ q,
                        const float* __restrict__ k,
                        const float* __restrict__ v,
                        float* __restrict__ out) {
    __shared__ float lds[2][LBUF + 4];  // +4: C-read of edge lanes may peek 1
                                        // float past the last slice

    const int band = blockIdx.x;       // 0..6
    const int n    = blockIdx.y;       // head
    const int b    = blockIdx.z;

    const int tid  = threadIdx.x;      // 0..447
    const int lane = tid & 63;
    const int wv   = tid >> 6;

    const int w = tid % WW;
    const int r = tid / WW;            // 0..7
    const int h0 = band * BAND;
    const int h  = h0 + r;

    // staged (clamped, contiguous) row range
    const int lo = (h0 - 2 < 0) ? 0 : h0 - 2;
    const int hi = (h0 + 9 > HH - 1) ? HH - 1 : h0 + 9;
    const int Sbytes = (hi - lo + 1) * WW * 4;   // 2240 or 2688

    // clamped column base: cols read are cb, cb+2, cb+4
    const int cb    = (w < 2) ? w : (w - 2);
    const bool isW0  = (w == 0);
    const bool wle1  = (w <= 1);
    const bool midB  = (w < 2) || (w == 54);
    const bool isW55 = (w == 55);

    // per-row LDS base offsets (reflected rows), + col base
    int rb[3];
#pragma unroll
    for (int i = 0; i < 3; ++i) {
        int rr = h + 2 * (i - 1);
        rr = (rr < 0) ? -rr : ((rr >= HH) ? (2 * HH - 2 - rr) : rr);
        rb[i] = (rr - lo) * WW + cb;
    }

    const int planebase = (b * CH + n * DD) * HW;     // first d-plane of head
    const float* qp = q + planebase + h * WW + w;
    const float* kstage = k + planebase + lo * WW;
    const float* vstage = v + planebase + lo * WW;

    // ---- kick off first k-chunk DMA, then load all q under it ----
    stage_chunk(kstage, lds[0], Sbytes, wv, lane);

    float qreg[DD];
#pragma unroll
    for (int d = 0; d < DD; ++d) qreg[d] = qp[d * HW];

    float sc[KSQ];
#pragma unroll
    for (int ii = 0; ii < KSQ; ++ii) sc[ii] = 0.f;

    __syncthreads();
    int cur = 0;

    // ---------------- pass 1: scores over 4 k-chunks ----------------
#pragma unroll
    for (int c = 0; c < NCHUNK; ++c) {
        if (c < NCHUNK - 1)
            stage_chunk(kstage + (c + 1) * DCH * HW, lds[cur ^ 1], Sbytes, wv, lane);
        else
            stage_chunk(vstage, lds[cur ^ 1], Sbytes, wv, lane);

        const float* Bf = lds[cur];
#pragma unroll
        for (int j = 0; j < DCH; ++j) {
            const float* Ls = Bf + j * SLICE;
            const float qj = qreg[c * DCH + j];
#pragma unroll
            for (int i = 0; i < 3; ++i) {
                const float* p = Ls + rb[i];
                float v0, v1, v2;
                WIN3(p, v0, v1, v2);
                sc[i * 3 + 0] = fmaf(qj, v0, sc[i * 3 + 0]);
                sc[i * 3 + 1] = fmaf(qj, v1, sc[i * 3 + 1]);
                sc[i * 3 + 2] = fmaf(qj, v2, sc[i * 3 + 2]);
            }
        }
        __syncthreads();
        cur ^= 1;
    }

    // ---------------- softmax over the 9 positions ----------------
    {
        float m = sc[0];
#pragma unroll
        for (int ii = 1; ii < KSQ; ++ii) m = fmaxf(m, sc[ii]);
        float sum = 0.f;
#pragma unroll
        for (int ii = 0; ii < KSQ; ++ii) {
            sc[ii] = __expf((sc[ii] - m) * SCALE);
            sum += sc[ii];
        }
        const float inv = 1.f / sum;
#pragma unroll
        for (int ii = 0; ii < KSQ; ++ii) sc[ii] *= inv;
    }

    // ---------------- pass 2: accumulate O[32] over 4 v-chunks ----------------
    float o[DD];
#pragma unroll
    for (int d = 0; d < DD; ++d) o[d] = 0.f;

#pragma unroll
    for (int c = 0; c < NCHUNK; ++c) {
        if (c < NCHUNK - 1)
            stage_chunk(vstage + (c + 1) * DCH * HW, lds[cur ^ 1], Sbytes, wv, lane);

        const float* Bf = lds[cur];
#pragma unroll
        for (int j = 0; j < DCH; ++j) {
            const float* Ls = Bf + j * SLICE;
            float acc = 0.f;
#pragma unroll
            for (int i = 0; i < 3; ++i) {
                const float* p = Ls + rb[i];
                float v0, v1, v2;
                WIN3(p, v0, v1, v2);
                acc = fmaf(sc[i * 3 + 0], v0,
                      fmaf(sc[i * 3 + 1], v1,
                      fmaf(sc[i * 3 + 2], v2, acc)));
            }
            o[c * DCH + j] = acc;
        }
        if (c < NCHUNK - 1) {
            __syncthreads();
            cur ^= 1;
        }
    }

    // ---- single contiguous 128B store per thread (full cache line) ----
    float* op = out + ((b * HH + h) * WW + w) * CH + n * DD;
#pragma unroll
    for (int d4 = 0; d4 < DD / 4; ++d4) {
        *(float4*)(op + d4 * 4) =
            make_float4(o[d4 * 4 + 0], o[d4 * 4 + 1],
                        o[d4 * 4 + 2], o[d4 * 4 + 3]);
    }
}

extern "C" void kernel_launch(void* const* d_in, const int* in_sizes, int n_in,
                              void* d_out, int out_size, void* d_ws, size_t ws_size,
                              hipStream_t stream) {
    const float* q = (const float*)d_in[0];
    const float* k = (const float*)d_in[1];
    const float* v = (const float*)d_in[2];
    float* out = (float*)d_out;

    dim3 grid(HH / BAND, NH, BB);   // 7 x 12 x 16 = 1344 blocks
    dilate_attn_kernel<<<grid, 448, 0, stream>>>(q, k, v, out);
}